// Round 2
// baseline (590.288 us; speedup 1.0000x reference)
//
#include <hip/hip_runtime.h>
#include <hip/hip_bf16.h>
#include <cstdint>
#include <cstddef>

// AttentionModule N=65536, C=D=512, L=16.
// Math: the L-expand makes softmax uniform (1/16) and all L columns identical,
// so the attention branch cancels exactly:
//   pos  = relu(features @ Wk^T)
//   pv   = sigmoid(pos @ Wvc^T) * pos
//   hmid = relu(bn1(features2 @ Wv1^T))
//   out  = relu(bn2(hmid @ Wv2^T)) + pv
// Wa / Wqk are mathematically unused.
//
// I/O dtype: float32 (per reference). Compute in bf16 MFMA, fp32 accum.
// ws layout (~130 MiB): pos | pv | Wk_b | Wv1_b | Wv2_b | Wvc_b  (all bf16).
#define DIM 512
#define NROWS 65536

typedef __bf16 bf16;
typedef __attribute__((ext_vector_type(8))) __bf16 bf16x8;
typedef __attribute__((ext_vector_type(4))) __bf16 bf16x4;
typedef __attribute__((ext_vector_type(4))) float f32x4;

__device__ __forceinline__ void async_copy16(const void* g, void* l) {
  __builtin_amdgcn_global_load_lds(
      (const __attribute__((address_space(1))) void*)g,
      (__attribute__((address_space(3))) void*)l, 16, 0, 0);
}

__device__ __forceinline__ float sigmoidf_(float x) {
  return 1.0f / (1.0f + __expf(-x));
}

// fp32 -> bf16 elementwise, vectorized x4. n4 = n/4.
__global__ __launch_bounds__(256) void cvt_f32_bf16(
    const float* __restrict__ s, bf16* __restrict__ d, int n4) {
  int i = blockIdx.x * 256 + threadIdx.x;
  if (i < n4) {
    f32x4 v = ((const f32x4*)s)[i];
    bf16x4 o;
    o[0] = (bf16)v[0]; o[1] = (bf16)v[1]; o[2] = (bf16)v[2]; o[3] = (bf16)v[3];
    ((bf16x4*)d)[i] = o;
  }
}

// C[m,n] = epi( sum_k A[m,k] * W[n,k] ),  W is bf16 [DIM][DIM] k-contiguous.
// AF32: A is fp32 (staged to LDS as fp32, cvt at fragment pack);
//       else A is bf16.
// EPI: 0 = relu                       (pos)
//      1 = sigmoid(acc) * Extra[m,n]  (pv)
//      2 = relu(bn(acc))              (hmid)
//      3 = relu(bn(acc)) + Extra      (out, fp32)
template <int EPI, bool AF32, typename OutT>
__global__ __launch_bounds__(256) void gemm_ep(
    const void* __restrict__ Av, const bf16* __restrict__ W,
    OutT* __restrict__ Out, const bf16* __restrict__ Extra,
    const float* __restrict__ bn_g, const float* __restrict__ bn_b,
    const float* __restrict__ bn_m, const float* __restrict__ bn_v) {
  // Unpadded: global_load_lds LDS dest must be contiguous in lane order.
  __shared__ __align__(16) char AsmRaw[AF32 ? 128 * 32 * 4 : 128 * 32 * 2];
  __shared__ __align__(16) bf16 Bsm[128 * 32];

  const int t = threadIdx.x;
  const int lane = t & 63;
  const int wv = t >> 6;
  const int wm = (wv & 1) * 64;
  const int wn = (wv >> 1) * 64;
  const int lr = lane & 15;   // row/col within 16x16 tile
  const int kq = lane >> 4;   // k-quad

  const int m0 = blockIdx.y * 128;
  const int n0 = blockIdx.x * 128;

  // B staging: 128x32 bf16 = 8 KiB = 512 x 16B; 256 thr x 2 chunks.
  const bf16* gB = W + (size_t)(n0 + (t >> 2)) * DIM + (t & 3) * 8;
  bf16* lB = &Bsm[t * 8];

  // A staging pointers.
  const float* gAf = nullptr; const bf16* gAh = nullptr;
  float* lAf = nullptr; bf16* lAh = nullptr;
  if constexpr (AF32) {
    // 128x32 fp32 = 16 KiB = 1024 x 16B; 256 thr x 4 chunks of 4 floats.
    gAf = (const float*)Av + (size_t)(m0 + (t >> 3)) * DIM + (t & 7) * 4;
    lAf = (float*)AsmRaw + t * 4;
  } else {
    gAh = (const bf16*)Av + (size_t)(m0 + (t >> 2)) * DIM + (t & 3) * 8;
    lAh = (bf16*)AsmRaw + t * 8;
  }

  f32x4 acc[4][4];
#pragma unroll
  for (int i = 0; i < 4; i++)
#pragma unroll
    for (int j = 0; j < 4; j++) acc[i][j] = (f32x4){0.f, 0.f, 0.f, 0.f};

  for (int kb = 0; kb < DIM; kb += 32) {
    if constexpr (AF32) {
      async_copy16(gAf + kb, lAf);
      async_copy16(gAf + kb + (size_t)32 * DIM, lAf + 1024);
      async_copy16(gAf + kb + (size_t)64 * DIM, lAf + 2048);
      async_copy16(gAf + kb + (size_t)96 * DIM, lAf + 3072);
    } else {
      async_copy16(gAh + kb, lAh);
      async_copy16(gAh + kb + (size_t)64 * DIM, lAh + 64 * 32);
    }
    async_copy16(gB + kb, lB);
    async_copy16(gB + kb + (size_t)64 * DIM, lB + 64 * 32);
    __syncthreads();  // drains vmcnt -> LDS tiles ready

    bf16x8 af[4], bfr[4];
#pragma unroll
    for (int i = 0; i < 4; i++) {
      // fragment: row = lane&15 (+tile), k = (lane>>4)*8 + j
      if constexpr (AF32) {
        const float* p = (const float*)AsmRaw + (wm + i * 16 + lr) * 32 + kq * 8;
        f32x4 lo = *(const f32x4*)p;
        f32x4 hi = *(const f32x4*)(p + 4);
        bf16x8 a;
        a[0] = (bf16)lo[0]; a[1] = (bf16)lo[1];
        a[2] = (bf16)lo[2]; a[3] = (bf16)lo[3];
        a[4] = (bf16)hi[0]; a[5] = (bf16)hi[1];
        a[6] = (bf16)hi[2]; a[7] = (bf16)hi[3];
        af[i] = a;
      } else {
        af[i] = *(const bf16x8*)((const bf16*)AsmRaw +
                                 (wm + i * 16 + lr) * 32 + kq * 8);
      }
      bfr[i] = *(const bf16x8*)&Bsm[(wn + i * 16 + lr) * 32 + kq * 8];
    }
#pragma unroll
    for (int i = 0; i < 4; i++)
#pragma unroll
      for (int j = 0; j < 4; j++)
        acc[i][j] = __builtin_amdgcn_mfma_f32_16x16x32_bf16(af[i], bfr[j],
                                                            acc[i][j], 0, 0, 0);
    __syncthreads();
  }

  // Epilogue. C/D layout: col = lane&15, row = (lane>>4)*4 + reg.
  float invj[4], bbj[4];
  if (EPI >= 2) {
#pragma unroll
    for (int j = 0; j < 4; j++) {
      int c = n0 + wn + j * 16 + lr;
      float iv = bn_g[c] * rsqrtf(bn_v[c] + 1e-5f);
      invj[j] = iv;
      bbj[j] = bn_b[c] - bn_m[c] * iv;
    }
  }
#pragma unroll
  for (int i = 0; i < 4; i++) {
#pragma unroll
    for (int r = 0; r < 4; r++) {
      size_t row = (size_t)(m0 + wm + i * 16 + kq * 4 + r) * DIM;
#pragma unroll
      for (int j = 0; j < 4; j++) {
        int c = n0 + wn + j * 16 + lr;
        float v = acc[i][j][r];
        if (EPI == 0) {
          v = fmaxf(v, 0.f);
        } else if (EPI == 1) {
          v = sigmoidf_(v) * (float)Extra[row + c];
        } else {
          v = fmaxf(v * invj[j] + bbj[j], 0.f);
          if (EPI == 3) v += (float)Extra[row + c];
        }
        Out[row + c] = (OutT)v;
      }
    }
  }
}

extern "C" void kernel_launch(void* const* d_in, const int* in_sizes, int n_in,
                              void* d_out, int out_size, void* d_ws,
                              size_t ws_size, hipStream_t stream) {
  const float* features  = (const float*)d_in[0];
  const float* features2 = (const float*)d_in[1];
  const float* Wk  = (const float*)d_in[2];
  const float* Wv1 = (const float*)d_in[3];
  const float* Wv2 = (const float*)d_in[4];
  const float* g1 = (const float*)d_in[5];
  const float* b1 = (const float*)d_in[6];
  const float* m1 = (const float*)d_in[7];
  const float* v1 = (const float*)d_in[8];
  const float* g2 = (const float*)d_in[9];
  const float* b2 = (const float*)d_in[10];
  const float* m2 = (const float*)d_in[11];
  const float* v2 = (const float*)d_in[12];
  // d_in[13] Wa, d_in[14] Wqk: cancelled, unused.
  const float* Wvc = (const float*)d_in[15];
  float* out = (float*)d_out;

  // ws (bf16): pos | pv | wk | wv1 | wv2 | wvc  ~= 130 MiB total.
  bf16* pos = (bf16*)d_ws;                     // later reused as hmid
  bf16* pv  = pos + (size_t)NROWS * DIM;
  bf16* wkb  = pv + (size_t)NROWS * DIM;
  bf16* wv1b = wkb + DIM * DIM;
  bf16* wv2b = wv1b + DIM * DIM;
  bf16* wvcb = wv2b + DIM * DIM;

  // Convert the 4 GEMM weight matrices to bf16 (512x512 each).
  {
    int n4 = DIM * DIM / 4;             // 65536
    dim3 cg(n4 / 256), cb(256);
    cvt_f32_bf16<<<cg, cb, 0, stream>>>(Wk, wkb, n4);
    cvt_f32_bf16<<<cg, cb, 0, stream>>>(Wv1, wv1b, n4);
    cvt_f32_bf16<<<cg, cb, 0, stream>>>(Wv2, wv2b, n4);
    cvt_f32_bf16<<<cg, cb, 0, stream>>>(Wvc, wvcb, n4);
  }

  dim3 grid(DIM / 128, NROWS / 128);  // (4, 512)
  dim3 block(256);

  // K1: pos = relu(features @ Wk^T)          (A fp32 on the fly)
  gemm_ep<0, true, bf16><<<grid, block, 0, stream>>>(
      features, wkb, pos, nullptr, nullptr, nullptr, nullptr, nullptr);
  // K2: pv = sigmoid(pos @ Wvc^T) * pos      (all bf16)
  gemm_ep<1, false, bf16><<<grid, block, 0, stream>>>(
      pos, wvcb, pv, pos, nullptr, nullptr, nullptr, nullptr);
  // K3: hmid = relu(bn1(features2 @ Wv1^T))  -> overwrites pos (dead)
  gemm_ep<2, true, bf16><<<grid, block, 0, stream>>>(
      features2, wv1b, pos, nullptr, g1, b1, m1, v1);
  // K4: out = relu(bn2(hmid @ Wv2^T)) + pv   (fp32 out)
  gemm_ep<3, false, float><<<grid, block, 0, stream>>>(
      pos, wv2b, out, pv, g2, b2, m2, v2);
}